// Round 8
// baseline (266.203 us; speedup 1.0000x reference)
//
#include <hip/hip_runtime.h>
#include <stdint.h>

static constexpr int EMB   = 1024;
static constexpr int HEADS = 16;
static constexpr int HD    = 64;
static constexpr int BATCH = 2;
static constexpr int SEQ   = 2048;
static constexpr int BT    = BATCH * SEQ;   // 4096 rows
static constexpr float QSC = 0.18033688011112042f;  // log2(e)/8

typedef short   short8  __attribute__((ext_vector_type(8)));
typedef float   float4v __attribute__((ext_vector_type(4)));

__device__ __forceinline__ ushort f2bf(float f) {          // RNE (epilogues)
    union { float f; uint32_t i; } v; v.f = f;
    uint32_t x = v.i;
    return (ushort)((x + 0x7FFFu + ((x >> 16) & 1u)) >> 16);
}
__device__ __forceinline__ ushort f2bf_rn(float f) {       // round-half-up, 2 VALU
    union { float f; uint32_t i; } v; v.f = f;
    return (ushort)((v.i + 0x8000u) >> 16);
}
__device__ __forceinline__ uint32_t pack2bf(float lo, float hi) {
    union { float f; uint32_t u; } a, b; a.f = lo; b.f = hi;
    uint32_t ra = a.u + 0x7FFFu + ((a.u >> 16) & 1u);
    uint32_t rb = b.u + 0x7FFFu + ((b.u >> 16) & 1u);
    return (rb & 0xFFFF0000u) | (ra >> 16);
}
__device__ __forceinline__ float fast_exp2(float x) {
#if __has_builtin(__builtin_amdgcn_exp2f)
    return __builtin_amdgcn_exp2f(x);   // raw v_exp_f32: 1 instr, -1e30 -> 0
#else
    return exp2f(x);
#endif
}

// async 16B global->LDS (DMA). LDS dest = wave-uniform base + lane*16.
__device__ __forceinline__ void async_ld16(const void* g, void* l) {
    __builtin_amdgcn_global_load_lds(
        (const __attribute__((address_space(1))) void*)g,
        (__attribute__((address_space(3))) void*)l,
        16, 0, 0);
}

// ---------------------------------------------------------------------------
// Pre-pass: convert fp32 inputs -> bf16 workspace. 8 elems/thread.
// ---------------------------------------------------------------------------
__global__ void cvt_all(const float* __restrict__ q, const float* __restrict__ k,
                        const float* __restrict__ v,
                        const float* __restrict__ wq, const float* __restrict__ wk,
                        const float* __restrict__ wv, const float* __restrict__ wo,
                        ushort* __restrict__ qb, ushort* __restrict__ kb,
                        ushort* __restrict__ vb,
                        ushort* __restrict__ wqb, ushort* __restrict__ wkb,
                        ushort* __restrict__ wvb, ushort* __restrict__ wob)
{
    int bid = blockIdx.x;
    const float* src; ushort* dst; size_t off;
    if (bid < 6144) {
        int seg = bid >> 11;
        src = seg == 0 ? q : (seg == 1 ? k : v);
        dst = seg == 0 ? qb : (seg == 1 ? kb : vb);
        off = (size_t)(bid & 2047) * 2048;
    } else {
        int t = bid - 6144, seg = t >> 9;
        src = seg == 0 ? wq : (seg == 1 ? wk : (seg == 2 ? wv : wo));
        dst = seg == 0 ? wqb : (seg == 1 ? wkb : (seg == 2 ? wvb : wob));
        off = (size_t)(t & 511) * 2048;
    }
    size_t base = off + (size_t)threadIdx.x * 8;
    float4 a0 = *(const float4*)(src + base);
    float4 a1 = *(const float4*)(src + base + 4);
    uint32_t o[4] = { pack2bf(a0.x, a0.y), pack2bf(a0.z, a0.w),
                      pack2bf(a1.x, a1.y), pack2bf(a1.z, a1.w) };
    *(uint4*)(dst + base) = *(uint4*)o;
}

// ---------------------------------------------------------------------------
// Core 128x128 GEMM tile (m97 structure): 4 waves, each 64x64 = 4x4 MFMA acc.
// Swizzled global_load_lds staging: LDS(rowgroup, lane) holds global chunk
// (lane&7)^(row&7) so b128 fragment reads are 2-way (free) at worst.
// ---------------------------------------------------------------------------
__device__ __forceinline__ void gemm_core_128(
    const ushort* __restrict__ A, const ushort* __restrict__ W,
    int m0, int n0, int K,
    ushort* As, ushort* Ws,
    int wid, int lane, float4v acc[4][4])
{
    const int lrow8 = lane >> 3;
    const int gc    = (lane & 7) ^ lrow8;
    const ushort* Ab = A + (size_t)m0 * K + gc * 8;
    const ushort* Wb = W + (size_t)n0 * K + gc * 8;
    const int wm = (wid >> 1) * 64;
    const int wn = (wid & 1) * 64;

    for (int k0 = 0; k0 < K; k0 += 64) {
        __syncthreads();
#pragma unroll
        for (int it = 0; it < 4; ++it) {
            int rg = it * 4 + wid;               // row group 0..15 (8 rows each)
            int row = rg * 8 + lrow8;
            async_ld16(Ab + (size_t)row * K + k0, &As[rg * 512]);
            async_ld16(Wb + (size_t)row * K + k0, &Ws[rg * 512]);
        }
        __syncthreads();
#pragma unroll
        for (int ks = 0; ks < 2; ++ks) {
            const int c = ks * 4 + (lane >> 4);
            short8 af[4], wf[4];
#pragma unroll
            for (int i = 0; i < 4; i++) {
                int row = wm + i * 16 + (lane & 15);
                af[i] = *(const short8*)&As[row * 64 + ((c ^ (row & 7)) * 8)];
            }
#pragma unroll
            for (int j = 0; j < 4; j++) {
                int row = wn + j * 16 + (lane & 15);
                wf[j] = *(const short8*)&Ws[row * 64 + ((c ^ (row & 7)) * 8)];
            }
#pragma unroll
            for (int i = 0; i < 4; i++)
#pragma unroll
                for (int j = 0; j < 4; j++)
                    acc[i][j] = __builtin_amdgcn_mfma_f32_16x16x32_bf16(af[i], wf[j], acc[i][j], 0, 0, 0);
        }
    }
}

// ---------------------------------------------------------------------------
// Fused Q/K/V projection GEMM: blockIdx.z selects {Q,K,V}.
// ---------------------------------------------------------------------------
__global__ __launch_bounds__(256, 3)
void gemm_qkv(const ushort* __restrict__ qb, const ushort* __restrict__ kb,
              const ushort* __restrict__ vb,
              const ushort* __restrict__ wqb, const ushort* __restrict__ wkb,
              const ushort* __restrict__ wvb,
              const float* __restrict__ bq, const float* __restrict__ bk,
              const float* __restrict__ bv,
              const float* __restrict__ cbq, const float* __restrict__ cbk,
              ushort* __restrict__ qc, ushort* __restrict__ kc,
              ushort* __restrict__ vt)
{
    __shared__ __align__(16) ushort As[128 * 64];
    __shared__ __align__(16) ushort Ws[128 * 64];

    const int z = blockIdx.z;
    const ushort* A    = z == 0 ? qb  : (z == 1 ? kb  : vb);
    const ushort* W    = z == 0 ? wqb : (z == 1 ? wkb : wvb);
    const float*  bias = z == 0 ? bq  : (z == 1 ? bk  : bv);
    const float*  clrb = z == 0 ? cbq : cbk;
    const float   scale = z == 0 ? QSC : 1.0f;

    const int tid  = threadIdx.x;
    const int wid  = tid >> 6;
    const int lane = tid & 63;
    const int m0 = blockIdx.y * 128;
    const int n0 = blockIdx.x * 128;
    const int wm = (wid >> 1) * 64;
    const int wn = (wid & 1) * 64;

    float4v acc[4][4];
#pragma unroll
    for (int i = 0; i < 4; i++)
#pragma unroll
        for (int j = 0; j < 4; j++) acc[i][j] = (float4v)0.0f;

    gemm_core_128(A, W, m0, n0, EMB, As, Ws, wid, lane, acc);

    // Epilogue. C/D: col=lane&15, row=(lane>>4)*4+reg  [m89]
    const int h = (n0 + wn) >> 6;   // head (64 cols == wave n-tile)
#pragma unroll
    for (int i = 0; i < 4; i++) {
        float ys[4][4];
#pragma unroll
        for (int j = 0; j < 4; j++) {
            float bj = bias[n0 + wn + j * 16 + (lane & 15)];
#pragma unroll
            for (int r = 0; r < 4; r++) ys[j][r] = acc[i][j][r] + bj;
        }
        const int rowb = m0 + wm + i * 16 + ((lane >> 4) << 2);

        if (z < 2) {
            float rs[4];
#pragma unroll
            for (int r = 0; r < 4; r++)
                rs[r] = ys[0][r] + ys[1][r] + ys[2][r] + ys[3][r];
#pragma unroll
            for (int r = 0; r < 4; r++)
#pragma unroll
                for (int off = 1; off < 16; off <<= 1)
                    rs[r] += __shfl_xor(rs[r], off, 64);
            ushort* Yb = z == 0 ? qc : kc;
#pragma unroll
            for (int j = 0; j < 4; j++) {
                int d = j * 16 + (lane & 15);
                float cb = clrb[h * HD + d];
#pragma unroll
                for (int r = 0; r < 4; r++) {
                    int row = rowb + r;
                    int b = row >> 11, t = row & (SEQ - 1);
                    Yb[((size_t)(b * HEADS + h) * SEQ + t) * HD + d] =
                        f2bf((ys[j][r] - rs[r] * (1.0f / 64.0f) + cb) * scale);
                }
            }
        } else {
#pragma unroll
            for (int j = 0; j < 4; j++) {
                int d = j * 16 + (lane & 15);
#pragma unroll
                for (int r = 0; r < 4; r++) {
                    int row = rowb + r;
                    int b = row >> 11, t = row & (SEQ - 1);
                    vt[((size_t)(b * HEADS + h) * HD + d) * SEQ + t] = f2bf(ys[j][r]);
                }
            }
        }
    }
}

// ---------------------------------------------------------------------------
// Output projection GEMM: fp32 row-major output.
// ---------------------------------------------------------------------------
__global__ __launch_bounds__(256, 3)
void gemm_out(const ushort* __restrict__ A, const ushort* __restrict__ W,
              const float* __restrict__ bias, float* __restrict__ Y)
{
    __shared__ __align__(16) ushort As[128 * 64];
    __shared__ __align__(16) ushort Ws[128 * 64];

    const int tid  = threadIdx.x;
    const int wid  = tid >> 6;
    const int lane = tid & 63;
    const int m0 = blockIdx.y * 128;
    const int n0 = blockIdx.x * 128;
    const int wm = (wid >> 1) * 64;
    const int wn = (wid & 1) * 64;

    float4v acc[4][4];
#pragma unroll
    for (int i = 0; i < 4; i++)
#pragma unroll
        for (int j = 0; j < 4; j++) acc[i][j] = (float4v)0.0f;

    gemm_core_128(A, W, m0, n0, EMB, As, Ws, wid, lane, acc);

#pragma unroll
    for (int i = 0; i < 4; i++) {
        const int rowb = m0 + wm + i * 16 + ((lane >> 4) << 2);
#pragma unroll
        for (int j = 0; j < 4; j++) {
            int col = n0 + wn + j * 16 + (lane & 15);
            float bj = bias[col];
#pragma unroll
            for (int r = 0; r < 4; r++)
                Y[(size_t)(rowb + r) * EMB + col] = acc[i][j][r] + bj;
        }
    }
}

// ---------------------------------------------------------------------------
// Flash attention, static softmax (scores provably small; Q pre-scaled by
// log2(e)/8 -> p=exp2(s), m==0). Per (b,h,64-q-tile) block, K-tile=64.
// LDS = 8K (K) + 8K (V) + 8.5K (P) = 24.5 KB -> 4 blocks/CU (grid 1024 = 4/CU,
// 16 waves/CU) to hide the QK->exp2->P->PV serial chain via wave overlap.
// P staged per-wave with odd stride 68 (conflict-free-ish writes+b128 reads).
// ---------------------------------------------------------------------------
__global__ __launch_bounds__(256, 4)
void attn_kernel(const ushort* __restrict__ qc,
                 const ushort* __restrict__ kc,
                 const ushort* __restrict__ vt,
                 const unsigned char* __restrict__ mask,
                 ushort* __restrict__ out)
{
    constexpr int PST = 68;   // P row stride (ushorts), odd dword stride
    __shared__ __align__(16) ushort Ks[64 * 64];
    __shared__ __align__(16) ushort Vs[64 * 64];
    __shared__ __align__(16) ushort Ps[4][16 * PST];

    const int tid  = threadIdx.x;
    const int wid  = tid >> 6;
    const int lane = tid & 63;

    const int bid = blockIdx.x;
    const int qt = bid & 31;
    const int h  = (bid >> 5) & 15;
    const int b  = bid >> 9;

    const ushort* qbase = qc + ((size_t)(b * HEADS + h)) * SEQ * HD;
    const ushort* kbase = kc + ((size_t)(b * HEADS + h)) * SEQ * HD;
    const ushort* vbase = vt + ((size_t)(b * HEADS + h)) * HD * SEQ;

    const int qrow = qt * 64 + wid * 16 + (lane & 15);
    short8 qf[2];
#pragma unroll
    for (int ks = 0; ks < 2; ++ks)
        qf[ks] = *(const short8*)(qbase + (size_t)qrow * HD + ks * 32 + (lane >> 4) * 8);

    float l_r[4] = {0.f, 0.f, 0.f, 0.f};
    float4v o[4];
#pragma unroll
    for (int j = 0; j < 4; j++) o[j] = (float4v)0.f;

    const int lrow8 = lane >> 3;
    const int gc    = (lane & 7) ^ lrow8;
    ushort* Pw = &Ps[wid][0];

    for (int kt = 0; kt < SEQ / 64; ++kt) {
        __syncthreads();
#pragma unroll
        for (int it = 0; it < 2; ++it) {   // K: 64 rows x 64 d
            int rg = it * 4 + wid;         // row-group 0..7 (8 rows each)
            int row = rg * 8 + lrow8;
            async_ld16(kbase + (size_t)(kt * 64 + row) * HD + gc * 8,
                       &Ks[rg * 512]);
        }
#pragma unroll
        for (int it = 0; it < 2; ++it) {   // V: 64 d-rows x 64 t
            int rg = it * 4 + wid;
            int row = rg * 8 + lrow8;
            async_ld16(vbase + (size_t)row * SEQ + kt * 64 + gc * 8,
                       &Vs[rg * 512]);
        }
        __syncthreads();

        // S = Q K^T (log2-scaled via Q)
        float4v s[4];
#pragma unroll
        for (int j = 0; j < 4; j++) {
            s[j] = (float4v)0.f;
#pragma unroll
            for (int ks = 0; ks < 2; ks++) {
                int row = j * 16 + (lane & 15);
                int c   = ks * 4 + (lane >> 4);
                short8 kf = *(const short8*)&Ks[row * 64 + ((c ^ (row & 7)) * 8)];
                s[j] = __builtin_amdgcn_mfma_f32_16x16x32_bf16(qf[ks], kf, s[j], 0, 0, 0);
            }
        }

        // mask -> exp2 -> accumulate l, write P (C-layout -> A-layout via LDS)
#pragma unroll
        for (int j = 0; j < 4; j++) {
            int key = kt * 64 + j * 16 + (lane & 15);
            float mz = mask[b * SEQ + key] ? -1e30f : 0.0f;
            int prow = ((lane >> 4) << 2) * PST + j * 16 + (lane & 15);
#pragma unroll
            for (int r = 0; r < 4; r++) {
                float p = fast_exp2(s[j][r] + mz);
                l_r[r] += p;
                Pw[prow + r * PST] = f2bf_rn(p);
            }
        }
        asm volatile("s_waitcnt lgkmcnt(0)" ::: "memory");   // wave-private RAW

        short8 pf[2];
#pragma unroll
        for (int ks = 0; ks < 2; ks++)
            pf[ks] = *(const short8*)&Pw[(lane & 15) * PST + ks * 32 + (lane >> 4) * 8];

        // O += P V
#pragma unroll
        for (int j = 0; j < 4; j++) {
            int d = j * 16 + (lane & 15);
#pragma unroll
            for (int ks = 0; ks < 2; ks++) {
                int c = ks * 4 + (lane >> 4);
                short8 vf = *(const short8*)&Vs[d * 64 + ((c ^ (d & 7)) * 8)];
                o[j] = __builtin_amdgcn_mfma_f32_16x16x32_bf16(pf[ks], vf, o[j], 0, 0, 0);
            }
        }
    }

#pragma unroll
    for (int r = 0; r < 4; r++)
#pragma unroll
        for (int off = 1; off < 16; off <<= 1)
            l_r[r] += __shfl_xor(l_r[r], off, 64);

    const int qrow_out = qt * 64 + wid * 16 + ((lane >> 4) << 2);
#pragma unroll
    for (int j = 0; j < 4; j++) {
        int d = j * 16 + (lane & 15);
#pragma unroll
        for (int r = 0; r < 4; r++) {
            float val = o[j][r] / l_r[r];
            out[((size_t)(b * SEQ + qrow_out + r)) * EMB + h * HD + d] = f2bf(val);
        }
    }
}

// ---------------------------------------------------------------------------
extern "C" void kernel_launch(void* const* d_in, const int* in_sizes, int n_in,
                              void* d_out, int out_size, void* d_ws, size_t ws_size,
                              hipStream_t stream)
{
    const float* query = (const float*)d_in[0];
    const float* key_  = (const float*)d_in[1];
    const float* value = (const float*)d_in[2];
    const unsigned char* mask = (const unsigned char*)d_in[3];
    const float* Wq  = (const float*)d_in[4];
    const float* bq  = (const float*)d_in[5];
    const float* Wk  = (const float*)d_in[6];
    const float* bk  = (const float*)d_in[7];
    const float* Wv  = (const float*)d_in[8];
    const float* bv  = (const float*)d_in[9];
    const float* Wo  = (const float*)d_in[10];
    const float* bo  = (const float*)d_in[11];
    const float* cbq = (const float*)d_in[12];
    const float* cbk = (const float*)d_in[13];

    ushort* ws = (ushort*)d_ws;
    const size_t n1 = (size_t)BT * EMB;   // 4M elems
    const size_t nw = (size_t)EMB * EMB;  // 1M elems
    ushort* qb  = ws;
    ushort* kb  = qb  + n1;
    ushort* vb  = kb  + n1;
    ushort* wqb = vb  + n1;
    ushort* wkb = wqb + nw;
    ushort* wvb = wkb + nw;
    ushort* wob = wvb + nw;
    ushort* qc  = wob + nw;           // (B,H,T,D) centered, *log2e/8
    ushort* kc  = qc  + n1;           // (B,H,T,D) centered
    ushort* vt  = kc  + n1;           // (B,H,D,T)
    ushort* ao  = qb;                 // reuse qb slot (stream-serialized)

    cvt_all<<<8192, 256, 0, stream>>>(query, key_, value, Wq, Wk, Wv, Wo,
                                      qb, kb, vb, wqb, wkb, wvb, wob);

    dim3 gq(EMB / 128, BT / 128, 3);
    gemm_qkv<<<gq, 256, 0, stream>>>(qb, kb, vb, wqb, wkb, wvb,
                                     bq, bk, bv, cbq, cbk, qc, kc, vt);

    attn_kernel<<<BATCH * HEADS * (SEQ / 64), 256, 0, stream>>>(qc, kc, vt, mask, ao);

    dim3 go(EMB / 128, BT / 128);
    gemm_out<<<go, 256, 0, stream>>>(ao, wob, bo, (float*)d_out);
}

// Round 9
// 259.045 us; speedup vs baseline: 1.0276x; 1.0276x over previous
//
#include <hip/hip_runtime.h>
#include <stdint.h>

static constexpr int EMB   = 1024;
static constexpr int HEADS = 16;
static constexpr int HD    = 64;
static constexpr int BATCH = 2;
static constexpr int SEQ   = 2048;
static constexpr int BT    = BATCH * SEQ;   // 4096 rows
static constexpr float QSC = 0.18033688011112042f;  // log2(e)/8

typedef short   short8  __attribute__((ext_vector_type(8)));
typedef float   float4v __attribute__((ext_vector_type(4)));

__device__ __forceinline__ ushort f2bf(float f) {          // RNE (epilogues)
    union { float f; uint32_t i; } v; v.f = f;
    uint32_t x = v.i;
    return (ushort)((x + 0x7FFFu + ((x >> 16) & 1u)) >> 16);
}
__device__ __forceinline__ ushort f2bf_rn(float f) {       // round-half-up, 2 VALU
    union { float f; uint32_t i; } v; v.f = f;
    return (ushort)((v.i + 0x8000u) >> 16);
}
__device__ __forceinline__ uint32_t pack2bf(float lo, float hi) {
    union { float f; uint32_t u; } a, b; a.f = lo; b.f = hi;
    uint32_t ra = a.u + 0x7FFFu + ((a.u >> 16) & 1u);
    uint32_t rb = b.u + 0x7FFFu + ((b.u >> 16) & 1u);
    return (rb & 0xFFFF0000u) | (ra >> 16);
}
__device__ __forceinline__ float fast_exp2(float x) {
#if __has_builtin(__builtin_amdgcn_exp2f)
    return __builtin_amdgcn_exp2f(x);   // raw v_exp_f32: 1 instr, -1e30 -> 0
#else
    return exp2f(x);
#endif
}

// async 16B global->LDS (DMA). LDS dest = wave-uniform base + lane*16.
__device__ __forceinline__ void async_ld16(const void* g, void* l) {
    __builtin_amdgcn_global_load_lds(
        (const __attribute__((address_space(1))) void*)g,
        (__attribute__((address_space(3))) void*)l,
        16, 0, 0);
}

// ---------------------------------------------------------------------------
// Pre-pass: convert fp32 inputs -> bf16 workspace. 8 elems/thread.
// ---------------------------------------------------------------------------
__global__ void cvt_all(const float* __restrict__ q, const float* __restrict__ k,
                        const float* __restrict__ v,
                        const float* __restrict__ wq, const float* __restrict__ wk,
                        const float* __restrict__ wv, const float* __restrict__ wo,
                        ushort* __restrict__ qb, ushort* __restrict__ kb,
                        ushort* __restrict__ vb,
                        ushort* __restrict__ wqb, ushort* __restrict__ wkb,
                        ushort* __restrict__ wvb, ushort* __restrict__ wob)
{
    int bid = blockIdx.x;
    const float* src; ushort* dst; size_t off;
    if (bid < 6144) {
        int seg = bid >> 11;
        src = seg == 0 ? q : (seg == 1 ? k : v);
        dst = seg == 0 ? qb : (seg == 1 ? kb : vb);
        off = (size_t)(bid & 2047) * 2048;
    } else {
        int t = bid - 6144, seg = t >> 9;
        src = seg == 0 ? wq : (seg == 1 ? wk : (seg == 2 ? wv : wo));
        dst = seg == 0 ? wqb : (seg == 1 ? wkb : (seg == 2 ? wvb : wob));
        off = (size_t)(t & 511) * 2048;
    }
    size_t base = off + (size_t)threadIdx.x * 8;
    float4 a0 = *(const float4*)(src + base);
    float4 a1 = *(const float4*)(src + base + 4);
    uint32_t o[4] = { pack2bf(a0.x, a0.y), pack2bf(a0.z, a0.w),
                      pack2bf(a1.x, a1.y), pack2bf(a1.z, a1.w) };
    *(uint4*)(dst + base) = *(uint4*)o;
}

// ---------------------------------------------------------------------------
// Core 128x128 GEMM tile (m97 structure): 4 waves, each 64x64 = 4x4 MFMA acc.
// Swizzled global_load_lds staging: LDS(rowgroup, lane) holds global chunk
// (lane&7)^(row&7) so b128 fragment reads are 2-way (free) at worst.
// ---------------------------------------------------------------------------
__device__ __forceinline__ void gemm_core_128(
    const ushort* __restrict__ A, const ushort* __restrict__ W,
    int m0, int n0, int K,
    ushort* As, ushort* Ws,
    int wid, int lane, float4v acc[4][4])
{
    const int lrow8 = lane >> 3;
    const int gc    = (lane & 7) ^ lrow8;
    const ushort* Ab = A + (size_t)m0 * K + gc * 8;
    const ushort* Wb = W + (size_t)n0 * K + gc * 8;
    const int wm = (wid >> 1) * 64;
    const int wn = (wid & 1) * 64;

    for (int k0 = 0; k0 < K; k0 += 64) {
        __syncthreads();
#pragma unroll
        for (int it = 0; it < 4; ++it) {
            int rg = it * 4 + wid;               // row group 0..15 (8 rows each)
            int row = rg * 8 + lrow8;
            async_ld16(Ab + (size_t)row * K + k0, &As[rg * 512]);
            async_ld16(Wb + (size_t)row * K + k0, &Ws[rg * 512]);
        }
        __syncthreads();
#pragma unroll
        for (int ks = 0; ks < 2; ++ks) {
            const int c = ks * 4 + (lane >> 4);
            short8 af[4], wf[4];
#pragma unroll
            for (int i = 0; i < 4; i++) {
                int row = wm + i * 16 + (lane & 15);
                af[i] = *(const short8*)&As[row * 64 + ((c ^ (row & 7)) * 8)];
            }
#pragma unroll
            for (int j = 0; j < 4; j++) {
                int row = wn + j * 16 + (lane & 15);
                wf[j] = *(const short8*)&Ws[row * 64 + ((c ^ (row & 7)) * 8)];
            }
#pragma unroll
            for (int i = 0; i < 4; i++)
#pragma unroll
                for (int j = 0; j < 4; j++)
                    acc[i][j] = __builtin_amdgcn_mfma_f32_16x16x32_bf16(af[i], wf[j], acc[i][j], 0, 0, 0);
        }
    }
}

// ---------------------------------------------------------------------------
// Fused Q/K/V projection GEMM: blockIdx.z selects {Q,K,V}.
// z=0,1: center + clr bias (+log2e/8 for Q), bf16 (B,H,T,D)
// z=2:   bf16 transposed (B,H,D,T)
// Epilogue packs the 128x128 tile through LDS (reusing staging memory) so
// global stores are 8x16B/thread with 128B coalescing instead of 64x2B.
// S stride 136 ushorts: 16B-aligned rows, <=4-way LDS write conflicts,
// conflict-free b128 reads.
// ---------------------------------------------------------------------------
__global__ __launch_bounds__(256, 3)
void gemm_qkv(const ushort* __restrict__ qb, const ushort* __restrict__ kb,
              const ushort* __restrict__ vb,
              const ushort* __restrict__ wqb, const ushort* __restrict__ wkb,
              const ushort* __restrict__ wvb,
              const float* __restrict__ bq, const float* __restrict__ bk,
              const float* __restrict__ bv,
              const float* __restrict__ cbq, const float* __restrict__ cbk,
              ushort* __restrict__ qc, ushort* __restrict__ kc,
              ushort* __restrict__ vt)
{
    constexpr int SST = 136;   // S row stride (ushorts)
    __shared__ __align__(16) ushort S[128 * SST];   // aliases As/Ws staging

    const int z = blockIdx.z;
    const ushort* A    = z == 0 ? qb  : (z == 1 ? kb  : vb);
    const ushort* W    = z == 0 ? wqb : (z == 1 ? wkb : wvb);
    const float*  bias = z == 0 ? bq  : (z == 1 ? bk  : bv);
    const float*  clrb = z == 0 ? cbq : cbk;
    const float   scale = z == 0 ? QSC : 1.0f;

    const int tid  = threadIdx.x;
    const int wid  = tid >> 6;
    const int lane = tid & 63;
    const int m0 = blockIdx.y * 128;
    const int n0 = blockIdx.x * 128;
    const int wm = (wid >> 1) * 64;
    const int wn = (wid & 1) * 64;

    float4v acc[4][4];
#pragma unroll
    for (int i = 0; i < 4; i++)
#pragma unroll
        for (int j = 0; j < 4; j++) acc[i][j] = (float4v)0.0f;

    gemm_core_128(A, W, m0, n0, EMB, S, S + 128 * 64, wid, lane, acc);

    __syncthreads();   // all waves done with staging LDS before S overwrite

    // Phase A: epilogue math, write bf16 tile into S.
    // C/D: col=lane&15, row=(lane>>4)*4+reg  [m89]
    const int h  = (n0 + wn) >> 6;
    const int ln = lane & 15;
#pragma unroll
    for (int i = 0; i < 4; i++) {
        float ys[4][4];
#pragma unroll
        for (int j = 0; j < 4; j++) {
            float bj = bias[n0 + wn + j * 16 + ln];
#pragma unroll
            for (int r = 0; r < 4; r++) ys[j][r] = acc[i][j][r] + bj;
        }
        const int lrow = wm + i * 16 + ((lane >> 4) << 2);  // local m

        if (z < 2) {
            float rs[4];
#pragma unroll
            for (int r = 0; r < 4; r++)
                rs[r] = ys[0][r] + ys[1][r] + ys[2][r] + ys[3][r];
#pragma unroll
            for (int r = 0; r < 4; r++)
#pragma unroll
                for (int off = 1; off < 16; off <<= 1)
                    rs[r] += __shfl_xor(rs[r], off, 64);
#pragma unroll
            for (int j = 0; j < 4; j++) {
                float cb = clrb[h * HD + ((wn + j * 16 + ln) & 63)];
#pragma unroll
                for (int r = 0; r < 4; r++)
                    S[(lrow + r) * SST + wn + j * 16 + ln] =
                        f2bf((ys[j][r] - rs[r] * (1.0f / 64.0f) + cb) * scale);
            }
        } else {  // V: store transposed into S: S[n_local][m_local]
#pragma unroll
            for (int j = 0; j < 4; j++)
#pragma unroll
                for (int r = 0; r < 4; r++)
                    S[(wn + j * 16 + ln) * SST + lrow + r] = f2bf(ys[j][r]);
        }
    }
    __syncthreads();

    // Phase B: packed copy-out. 8 iters x 16B per thread, 128B coalesced.
    const int hbase = n0 >> 6;
    const int bloc  = m0 >> 11;
    const int tloc0 = m0 & (SEQ - 1);
    ushort* Yb = z == 0 ? qc : kc;
#pragma unroll
    for (int p = 0; p < 8; ++p) {
        int g = p * 256 + tid;
        int row = g >> 4, ch = g & 15;
        short8 val = *(const short8*)&S[row * SST + ch * 8];
        if (z < 2) {
            int gm = m0 + row;
            int bb = gm >> 11, tt = gm & (SEQ - 1);
            int hh = hbase + (ch >> 3);
            int d0 = (ch * 8) & 63;
            *(short8*)(Yb + (((size_t)(bb * HEADS + hh) * SEQ + tt) * HD + d0)) = val;
        } else {
            int nn = n0 + row;
            int hh = nn >> 6, dd = nn & 63;
            *(short8*)(vt + (((size_t)(bloc * HEADS + hh) * HD + dd) * SEQ
                             + tloc0 + ch * 8)) = val;
        }
    }
}

// ---------------------------------------------------------------------------
// Output projection GEMM: fp32 row-major output (coalesced dword stores).
// ---------------------------------------------------------------------------
__global__ __launch_bounds__(256, 3)
void gemm_out(const ushort* __restrict__ A, const ushort* __restrict__ W,
              const float* __restrict__ bias, float* __restrict__ Y)
{
    __shared__ __align__(16) ushort As[128 * 64];
    __shared__ __align__(16) ushort Ws[128 * 64];

    const int tid  = threadIdx.x;
    const int wid  = tid >> 6;
    const int lane = tid & 63;
    const int m0 = blockIdx.y * 128;
    const int n0 = blockIdx.x * 128;
    const int wm = (wid >> 1) * 64;
    const int wn = (wid & 1) * 64;

    float4v acc[4][4];
#pragma unroll
    for (int i = 0; i < 4; i++)
#pragma unroll
        for (int j = 0; j < 4; j++) acc[i][j] = (float4v)0.0f;

    gemm_core_128(A, W, m0, n0, EMB, As, Ws, wid, lane, acc);

#pragma unroll
    for (int i = 0; i < 4; i++) {
        const int rowb = m0 + wm + i * 16 + ((lane >> 4) << 2);
#pragma unroll
        for (int j = 0; j < 4; j++) {
            int col = n0 + wn + j * 16 + (lane & 15);
            float bj = bias[col];
#pragma unroll
            for (int r = 0; r < 4; r++)
                Y[(size_t)(rowb + r) * EMB + col] = acc[i][j][r] + bj;
        }
    }
}

// ---------------------------------------------------------------------------
// Flash attention — measured-best config (R6: 80.8 us): 64-q blocks,
// K-tile=128, LDS ~49 KB, 2 blocks/CU. Static softmax (Q pre-scaled by
// log2(e)/8 -> p=exp2(s), m==0), per-lane l reduced once at the end.
// ---------------------------------------------------------------------------
__global__ __launch_bounds__(256, 3)
void attn_kernel(const ushort* __restrict__ qc,
                 const ushort* __restrict__ kc,
                 const ushort* __restrict__ vt,
                 const unsigned char* __restrict__ mask,
                 ushort* __restrict__ out)
{
    __shared__ __align__(16) ushort Ks[128 * 64];
    __shared__ __align__(16) ushort Vs[64 * 128];
    __shared__ __align__(16) ushort Ps[4][16 * 136];

    const int tid  = threadIdx.x;
    const int wid  = tid >> 6;
    const int lane = tid & 63;

    const int bid = blockIdx.x;
    const int qt = bid & 31;
    const int h  = (bid >> 5) & 15;
    const int b  = bid >> 9;

    const ushort* qbase = qc + ((size_t)(b * HEADS + h)) * SEQ * HD;
    const ushort* kbase = kc + ((size_t)(b * HEADS + h)) * SEQ * HD;
    const ushort* vbase = vt + ((size_t)(b * HEADS + h)) * HD * SEQ;

    const int qrow = qt * 64 + wid * 16 + (lane & 15);
    short8 qf[2];
#pragma unroll
    for (int ks = 0; ks < 2; ++ks)
        qf[ks] = *(const short8*)(qbase + (size_t)qrow * HD + ks * 32 + (lane >> 4) * 8);

    float l_r[4] = {0.f, 0.f, 0.f, 0.f};
    float4v o[4];
#pragma unroll
    for (int j = 0; j < 4; j++) o[j] = (float4v)0.f;

    const int lrow8 = lane >> 3;
    const int gcK   = (lane & 7) ^ lrow8;
    ushort* Pw = &Ps[wid][0];

    for (int kt = 0; kt < SEQ / 128; ++kt) {
        __syncthreads();
#pragma unroll
        for (int it = 0; it < 4; ++it) {   // K: 128x64
            int row = (it * 4 + wid) * 8 + lrow8;
            async_ld16(kbase + (size_t)(kt * 128 + row) * HD + gcK * 8,
                       &Ks[(it * 4 + wid) * 512]);
        }
#pragma unroll
        for (int it = 0; it < 4; ++it) {   // V: 64x128
            int row = (it * 4 + wid) * 4 + (lane >> 4);
            int gc  = (lane & 15) ^ (row & 15);
            async_ld16(vbase + (size_t)row * SEQ + kt * 128 + gc * 8,
                       &Vs[(it * 4 + wid) * 512]);
        }
        __syncthreads();

        float4v s[8];
#pragma unroll
        for (int j = 0; j < 8; j++) {
            s[j] = (float4v)0.f;
#pragma unroll
            for (int ks = 0; ks < 2; ks++) {
                int row = j * 16 + (lane & 15);
                int c   = ks * 4 + (lane >> 4);
                short8 kf = *(const short8*)&Ks[row * 64 + ((c ^ (row & 7)) * 8)];
                s[j] = __builtin_amdgcn_mfma_f32_16x16x32_bf16(qf[ks], kf, s[j], 0, 0, 0);
            }
        }

        // mask -> exp2 -> accumulate l, write P (C-layout -> A-layout via LDS)
#pragma unroll
        for (int j = 0; j < 8; j++) {
            int key = kt * 128 + j * 16 + (lane & 15);
            float mz = mask[b * SEQ + key] ? -1e30f : 0.0f;
            int prow = ((lane >> 4) << 2) * 136 + j * 16 + (lane & 15);
#pragma unroll
            for (int r = 0; r < 4; r++) {
                float p = fast_exp2(s[j][r] + mz);
                l_r[r] += p;
                Pw[prow + r * 136] = f2bf_rn(p);
            }
        }
        asm volatile("s_waitcnt lgkmcnt(0)" ::: "memory");   // wave-private RAW

        short8 pf[4];
#pragma unroll
        for (int ks = 0; ks < 4; ks++)
            pf[ks] = *(const short8*)&Pw[(lane & 15) * 136 + ks * 32 + (lane >> 4) * 8];

#pragma unroll
        for (int j = 0; j < 4; j++) {
            int d = j * 16 + (lane & 15);
#pragma unroll
            for (int ks = 0; ks < 4; ks++) {
                int c = ks * 4 + (lane >> 4);
                short8 vf = *(const short8*)&Vs[d * 128 + ((c ^ (d & 15)) * 8)];
                o[j] = __builtin_amdgcn_mfma_f32_16x16x32_bf16(pf[ks], vf, o[j], 0, 0, 0);
            }
        }
    }

#pragma unroll
    for (int r = 0; r < 4; r++)
#pragma unroll
        for (int off = 1; off < 16; off <<= 1)
            l_r[r] += __shfl_xor(l_r[r], off, 64);

    const int qrow_out = qt * 64 + wid * 16 + ((lane >> 4) << 2);
#pragma unroll
    for (int j = 0; j < 4; j++) {
        int d = j * 16 + (lane & 15);
#pragma unroll
        for (int r = 0; r < 4; r++) {
            float val = o[j][r] / l_r[r];
            out[((size_t)(b * SEQ + qrow_out + r)) * EMB + h * HD + d] = f2bf(val);
        }
    }
}

// ---------------------------------------------------------------------------
extern "C" void kernel_launch(void* const* d_in, const int* in_sizes, int n_in,
                              void* d_out, int out_size, void* d_ws, size_t ws_size,
                              hipStream_t stream)
{
    const float* query = (const float*)d_in[0];
    const float* key_  = (const float*)d_in[1];
    const float* value = (const float*)d_in[2];
    const unsigned char* mask = (const unsigned char*)d_in[3];
    const float* Wq  = (const float*)d_in[4];
    const float* bq  = (const float*)d_in[5];
    const float* Wk  = (const float*)d_in[6];
    const float* bk  = (const float*)d_in[7];
    const float* Wv  = (const float*)d_in[8];
    const float* bv  = (const float*)d_in[9];
    const float* Wo  = (const float*)d_in[10];
    const float* bo  = (const float*)d_in[11];
    const float* cbq = (const float*)d_in[12];
    const float* cbk = (const float*)d_in[13];

    ushort* ws = (ushort*)d_ws;
    const size_t n1 = (size_t)BT * EMB;   // 4M elems
    const size_t nw = (size_t)EMB * EMB;  // 1M elems
    ushort* qb  = ws;
    ushort* kb  = qb  + n1;
    ushort* vb  = kb  + n1;
    ushort* wqb = vb  + n1;
    ushort* wkb = wqb + nw;
    ushort* wvb = wkb + nw;
    ushort* wob = wvb + nw;
    ushort* qc  = wob + nw;           // (B,H,T,D) centered, *log2e/8
    ushort* kc  = qc  + n1;           // (B,H,T,D) centered
    ushort* vt  = kc  + n1;           // (B,H,D,T)
    ushort* ao  = qb;                 // reuse qb slot (stream-serialized)

    cvt_all<<<8192, 256, 0, stream>>>(query, key_, value, Wq, Wk, Wv, Wo,
                                      qb, kb, vb, wqb, wkb, wvb, wob);

    dim3 gq(EMB / 128, BT / 128, 3);
    gemm_qkv<<<gq, 256, 0, stream>>>(qb, kb, vb, wqb, wkb, wvb,
                                     bq, bk, bv, cbq, cbk, qc, kc, vt);

    attn_kernel<<<BATCH * HEADS * (SEQ / 64), 256, 0, stream>>>(qc, kc, vt, mask, ao);

    dim3 go(EMB / 128, BT / 128);
    gemm_out<<<go, 256, 0, stream>>>(ao, wob, bo, (float*)d_out);
}

// Round 10
// 250.998 us; speedup vs baseline: 1.0606x; 1.0321x over previous
//
#include <hip/hip_runtime.h>
#include <stdint.h>

static constexpr int EMB   = 1024;
static constexpr int HEADS = 16;
static constexpr int HD    = 64;
static constexpr int BATCH = 2;
static constexpr int SEQ   = 2048;
static constexpr int BT    = BATCH * SEQ;   // 4096 rows
static constexpr float QSC = 0.18033688011112042f;  // log2(e)/8

typedef short   short8  __attribute__((ext_vector_type(8)));
typedef float   float4v __attribute__((ext_vector_type(4)));

__device__ __forceinline__ ushort f2bf(float f) {          // RNE
    union { float f; uint32_t i; } v; v.f = f;
    uint32_t x = v.i;
    return (ushort)((x + 0x7FFFu + ((x >> 16) & 1u)) >> 16);
}
__device__ __forceinline__ ushort f2bf_rn(float f) {       // round-half-up, 2 VALU
    union { float f; uint32_t i; } v; v.f = f;
    return (ushort)((v.i + 0x8000u) >> 16);
}
__device__ __forceinline__ uint32_t pack2bf(float lo, float hi) {
    union { float f; uint32_t u; } a, b; a.f = lo; b.f = hi;
    uint32_t ra = a.u + 0x7FFFu + ((a.u >> 16) & 1u);
    uint32_t rb = b.u + 0x7FFFu + ((b.u >> 16) & 1u);
    return (rb & 0xFFFF0000u) | (ra >> 16);
}
__device__ __forceinline__ float fast_exp2(float x) {
#if __has_builtin(__builtin_amdgcn_exp2f)
    return __builtin_amdgcn_exp2f(x);   // raw v_exp_f32: -1e30 -> 0
#else
    return exp2f(x);
#endif
}

// async 16B global->LDS (DMA). LDS dest = wave-uniform base + lane*16.
__device__ __forceinline__ void async_ld16(const void* g, void* l) {
    __builtin_amdgcn_global_load_lds(
        (const __attribute__((address_space(1))) void*)g,
        (__attribute__((address_space(3))) void*)l,
        16, 0, 0);
}

// ---------------------------------------------------------------------------
// Pre-pass: convert fp32 inputs -> bf16 workspace. 8 elems/thread.
// ---------------------------------------------------------------------------
__global__ void cvt_all(const float* __restrict__ q, const float* __restrict__ k,
                        const float* __restrict__ v,
                        const float* __restrict__ wq, const float* __restrict__ wk,
                        const float* __restrict__ wv, const float* __restrict__ wo,
                        ushort* __restrict__ qb, ushort* __restrict__ kb,
                        ushort* __restrict__ vb,
                        ushort* __restrict__ wqb, ushort* __restrict__ wkb,
                        ushort* __restrict__ wvb, ushort* __restrict__ wob)
{
    int bid = blockIdx.x;
    const float* src; ushort* dst; size_t off;
    if (bid < 6144) {
        int seg = bid >> 11;
        src = seg == 0 ? q : (seg == 1 ? k : v);
        dst = seg == 0 ? qb : (seg == 1 ? kb : vb);
        off = (size_t)(bid & 2047) * 2048;
    } else {
        int t = bid - 6144, seg = t >> 9;
        src = seg == 0 ? wq : (seg == 1 ? wk : (seg == 2 ? wv : wo));
        dst = seg == 0 ? wqb : (seg == 1 ? wkb : (seg == 2 ? wvb : wob));
        off = (size_t)(t & 511) * 2048;
    }
    size_t base = off + (size_t)threadIdx.x * 8;
    float4 a0 = *(const float4*)(src + base);
    float4 a1 = *(const float4*)(src + base + 4);
    uint32_t o[4] = { pack2bf(a0.x, a0.y), pack2bf(a0.z, a0.w),
                      pack2bf(a1.x, a1.y), pack2bf(a1.z, a1.w) };
    *(uint4*)(dst + base) = *(uint4*)o;
}

// ---------------------------------------------------------------------------
// Core 128x128 NT GEMM tile: 4 waves, each 64x64 = 4x4 MFMA acc.
// Swizzled global_load_lds staging; b128 fragment reads 2-way worst (free).
// ---------------------------------------------------------------------------
__device__ __forceinline__ void gemm_core_128(
    const ushort* __restrict__ A, const ushort* __restrict__ W,
    int m0, int n0, int K,
    ushort* As, ushort* Ws,
    int wid, int lane, float4v acc[4][4])
{
    const int lrow8 = lane >> 3;
    const int gc    = (lane & 7) ^ lrow8;
    const ushort* Ab = A + (size_t)m0 * K + gc * 8;
    const ushort* Wb = W + (size_t)n0 * K + gc * 8;
    const int wm = (wid >> 1) * 64;
    const int wn = (wid & 1) * 64;

    for (int k0 = 0; k0 < K; k0 += 64) {
        __syncthreads();
#pragma unroll
        for (int it = 0; it < 4; ++it) {
            int rg = it * 4 + wid;
            int row = rg * 8 + lrow8;
            async_ld16(Ab + (size_t)row * K + k0, &As[rg * 512]);
            async_ld16(Wb + (size_t)row * K + k0, &Ws[rg * 512]);
        }
        __syncthreads();
#pragma unroll
        for (int ks = 0; ks < 2; ++ks) {
            const int c = ks * 4 + (lane >> 4);
            short8 af[4], wf[4];
#pragma unroll
            for (int i = 0; i < 4; i++) {
                int row = wm + i * 16 + (lane & 15);
                af[i] = *(const short8*)&As[row * 64 + ((c ^ (row & 7)) * 8)];
            }
#pragma unroll
            for (int j = 0; j < 4; j++) {
                int row = wn + j * 16 + (lane & 15);
                wf[j] = *(const short8*)&Ws[row * 64 + ((c ^ (row & 7)) * 8)];
            }
#pragma unroll
            for (int i = 0; i < 4; i++)
#pragma unroll
                for (int j = 0; j < 4; j++)
                    acc[i][j] = __builtin_amdgcn_mfma_f32_16x16x32_bf16(af[i], wf[j], acc[i][j], 0, 0, 0);
        }
    }
}

// ---------------------------------------------------------------------------
// Fused Q/K/V projection. 1D grid of 768, z = bid>>8.
// z=0 (Q), z=1 (K): standard orientation, centered + clr bias (+QSC for Q),
//   output row-major (B*T, EMB) bf16 -> fully coalesced.
// z=2 (V): TRANSPOSED GEMM (A=Wv, W=V-input): out[d][t] = sum_k Wv[d,k]V[t,k],
//   directly yields vt (B,H,D,T) with coalesced row stores — no scatter.
// Epilogue packs tile through LDS S: copy-out 8 x 16B/thread, 128B coalesced.
// ---------------------------------------------------------------------------
__global__ __launch_bounds__(256, 3)
void gemm_qkv(const ushort* __restrict__ qb, const ushort* __restrict__ kb,
              const ushort* __restrict__ vb,
              const ushort* __restrict__ wqb, const ushort* __restrict__ wkb,
              const ushort* __restrict__ wvb,
              const float* __restrict__ bq, const float* __restrict__ bk,
              const float* __restrict__ bv,
              const float* __restrict__ cbq, const float* __restrict__ cbk,
              ushort* __restrict__ qc, ushort* __restrict__ kc,
              ushort* __restrict__ vt)
{
    constexpr int SST = 136;
    __shared__ __align__(16) ushort S[128 * SST];   // aliases staging (first 32 KB)

    const int bid = blockIdx.x;
    const int z = bid >> 8;
    const int r = bid & 255;
    int m0, n0;
    if (z < 2) { m0 = (r >> 3) * 128; n0 = (r & 7) * 128; }   // m: 4096 rows, n: 1024
    else       { m0 = (r & 7) * 128;  n0 = (r >> 3) * 128; }  // m: 1024 (e), n: 4096 (b,t)

    const ushort* A = z == 0 ? qb  : (z == 1 ? kb  : wvb);
    const ushort* W = z == 0 ? wqb : (z == 1 ? wkb : vb);

    const int tid  = threadIdx.x;
    const int wid  = tid >> 6;
    const int lane = tid & 63;
    const int wm = (wid >> 1) * 64;
    const int wn = (wid & 1) * 64;
    const int ln = lane & 15;

    float4v acc[4][4];
#pragma unroll
    for (int i = 0; i < 4; i++)
#pragma unroll
        for (int j = 0; j < 4; j++) acc[i][j] = (float4v)0.0f;

    gemm_core_128(A, W, m0, n0, EMB, S, S + 128 * 64, wid, lane, acc);

    __syncthreads();   // staging LDS dead; reuse as S

    // Phase A: epilogue math -> S.  C/D: col=lane&15, row=(lane>>4)*4+reg [m89]
    if (z < 2) {
        const float* bias = z == 0 ? bq : bk;
        const float* clrb = z == 0 ? cbq : cbk;
        const float  scale = z == 0 ? QSC : 1.0f;
        const int h = (n0 + wn) >> 6;   // head = wave n-tile (64 cols)
#pragma unroll
        for (int i = 0; i < 4; i++) {
            float ys[4][4];
#pragma unroll
            for (int j = 0; j < 4; j++) {
                float bj = bias[n0 + wn + j * 16 + ln];
#pragma unroll
                for (int rr = 0; rr < 4; rr++) ys[j][rr] = acc[i][j][rr] + bj;
            }
            const int lrow = wm + i * 16 + ((lane >> 4) << 2);
            float rs[4];
#pragma unroll
            for (int rr = 0; rr < 4; rr++)
                rs[rr] = ys[0][rr] + ys[1][rr] + ys[2][rr] + ys[3][rr];
#pragma unroll
            for (int rr = 0; rr < 4; rr++)
#pragma unroll
                for (int off = 1; off < 16; off <<= 1)
                    rs[rr] += __shfl_xor(rs[rr], off, 64);
#pragma unroll
            for (int j = 0; j < 4; j++) {
                float cb = clrb[h * HD + ((wn + j * 16 + ln) & 63)];
#pragma unroll
                for (int rr = 0; rr < 4; rr++)
                    S[(lrow + rr) * SST + wn + j * 16 + ln] =
                        f2bf((ys[j][rr] - rs[rr] * (1.0f / 64.0f) + cb) * scale);
            }
        }
    } else {
        // V transposed: row m = output e-dim -> bias per ROW (bv[m]).
#pragma unroll
        for (int i = 0; i < 4; i++) {
            const int lrow = wm + i * 16 + ((lane >> 4) << 2);
            float bvr[4];
#pragma unroll
            for (int rr = 0; rr < 4; rr++) bvr[rr] = bv[m0 + lrow + rr];
#pragma unroll
            for (int j = 0; j < 4; j++)
#pragma unroll
                for (int rr = 0; rr < 4; rr++)
                    S[(lrow + rr) * SST + wn + j * 16 + ln] =
                        f2bf(acc[i][j][rr] + bvr[rr]);
        }
    }
    __syncthreads();

    // Phase B: packed copy-out, 8 x 16B/thread, 128B coalesced.
    ushort* Yb = z == 0 ? qc : (z == 1 ? kc : vt);
#pragma unroll
    for (int p = 0; p < 8; ++p) {
        int g = p * 256 + tid;
        int row = g >> 4, ch = g & 15;
        short8 val = *(const short8*)&S[row * SST + ch * 8];
        if (z < 2) {
            // row-major (B*T, EMB)
            *(short8*)(Yb + (size_t)(m0 + row) * EMB + n0 + ch * 8) = val;
        } else {
            // vt (B,H,D,T): e = m0+row; n-col = n0+ch*8 (single b per tile)
            int e = m0 + row;
            int ng = n0 + ch * 8;
            int bb = ng >> 11, tt = ng & (SEQ - 1);
            int hh = e >> 6, dd = e & 63;
            *(short8*)(Yb + ((size_t)(bb * HEADS + hh) * HD + dd) * SEQ + tt) = val;
        }
    }
}

// ---------------------------------------------------------------------------
// Output projection GEMM, 64x128 tile (grid 512 = 2 blocks/CU for barrier
// hiding; the 128x128 version ran 256 blocks = 1/CU with zero overlap).
// 4 waves: 32x64 each (acc 2x4). fp32 row-major output.
// ---------------------------------------------------------------------------
__global__ __launch_bounds__(256, 2)
void gemm_out(const ushort* __restrict__ A, const ushort* __restrict__ W,
              const float* __restrict__ bias, float* __restrict__ Y)
{
    __shared__ __align__(16) ushort As[64 * 64];
    __shared__ __align__(16) ushort Ws[128 * 64];

    const int tid  = threadIdx.x;
    const int wid  = tid >> 6;
    const int lane = tid & 63;
    const int m0 = blockIdx.y * 64;
    const int n0 = blockIdx.x * 128;
    const int wm = (wid >> 1) * 32;
    const int wn = (wid & 1) * 64;

    float4v acc[2][4];
#pragma unroll
    for (int i = 0; i < 2; i++)
#pragma unroll
        for (int j = 0; j < 4; j++) acc[i][j] = (float4v)0.0f;

    const int lrow8 = lane >> 3;
    const int gc    = (lane & 7) ^ lrow8;
    const ushort* Ab = A + (size_t)m0 * EMB + gc * 8;
    const ushort* Wb = W + (size_t)n0 * EMB + gc * 8;

    for (int k0 = 0; k0 < EMB; k0 += 64) {
        __syncthreads();
#pragma unroll
        for (int it = 0; it < 6; ++it) {
            int rg = it * 4 + wid;          // 0..23: 8 A-rowgroups, 16 W-rowgroups
            if (rg < 8) {
                int row = rg * 8 + lrow8;
                async_ld16(Ab + (size_t)row * EMB + k0, &As[rg * 512]);
            } else {
                int wg = rg - 8;
                int row = wg * 8 + lrow8;
                async_ld16(Wb + (size_t)row * EMB + k0, &Ws[wg * 512]);
            }
        }
        __syncthreads();
#pragma unroll
        for (int ks = 0; ks < 2; ++ks) {
            const int c = ks * 4 + (lane >> 4);
            short8 af[2], wf[4];
#pragma unroll
            for (int i = 0; i < 2; i++) {
                int row = wm + i * 16 + (lane & 15);
                af[i] = *(const short8*)&As[row * 64 + ((c ^ (row & 7)) * 8)];
            }
#pragma unroll
            for (int j = 0; j < 4; j++) {
                int row = wn + j * 16 + (lane & 15);
                wf[j] = *(const short8*)&Ws[row * 64 + ((c ^ (row & 7)) * 8)];
            }
#pragma unroll
            for (int i = 0; i < 2; i++)
#pragma unroll
                for (int j = 0; j < 4; j++)
                    acc[i][j] = __builtin_amdgcn_mfma_f32_16x16x32_bf16(af[i], wf[j], acc[i][j], 0, 0, 0);
        }
    }

#pragma unroll
    for (int i = 0; i < 2; i++) {
        const int rowb = m0 + wm + i * 16 + ((lane >> 4) << 2);
#pragma unroll
        for (int j = 0; j < 4; j++) {
            int col = n0 + wn + j * 16 + (lane & 15);
            float bj = bias[col];
#pragma unroll
            for (int rr = 0; rr < 4; rr++)
                Y[(size_t)(rowb + rr) * EMB + col] = acc[i][j][rr] + bj;
        }
    }
}

// ---------------------------------------------------------------------------
// Flash attention — measured-best config (R6/R9: ~79-81 us): 64-q blocks,
// K-tile=128. Static softmax (Q pre-scaled by log2(e)/8 -> p=exp2(s), m==0).
// qc,kc now ROW-MAJOR (B*T, EMB): loads take the head's 64-col slice at
// stride EMB (same DMA instruction count). vt stays (B,H,D,T).
// ---------------------------------------------------------------------------
__global__ __launch_bounds__(256, 3)
void attn_kernel(const ushort* __restrict__ qc,
                 const ushort* __restrict__ kc,
                 const ushort* __restrict__ vt,
                 const unsigned char* __restrict__ mask,
                 ushort* __restrict__ out)
{
    __shared__ __align__(16) ushort Ks[128 * 64];
    __shared__ __align__(16) ushort Vs[64 * 128];
    __shared__ __align__(16) ushort Ps[4][16 * 136];

    const int tid  = threadIdx.x;
    const int wid  = tid >> 6;
    const int lane = tid & 63;

    const int bid = blockIdx.x;
    const int qt = bid & 31;
    const int h  = (bid >> 5) & 15;
    const int b  = bid >> 9;

    const ushort* vbase = vt + ((size_t)(b * HEADS + h)) * HD * SEQ;

    const int qrow = qt * 64 + wid * 16 + (lane & 15);
    short8 qf[2];
#pragma unroll
    for (int ks = 0; ks < 2; ++ks)
        qf[ks] = *(const short8*)(qc + (size_t)(b * SEQ + qrow) * EMB
                                  + h * HD + ks * 32 + (lane >> 4) * 8);

    float l_r[4] = {0.f, 0.f, 0.f, 0.f};
    float4v o[4];
#pragma unroll
    for (int j = 0; j < 4; j++) o[j] = (float4v)0.f;

    const int lrow8 = lane >> 3;
    const int gcK   = (lane & 7) ^ lrow8;
    ushort* Pw = &Ps[wid][0];

    for (int kt = 0; kt < SEQ / 128; ++kt) {
        __syncthreads();
#pragma unroll
        for (int it = 0; it < 4; ++it) {   // K: 128 t-rows x 64 d
            int row = (it * 4 + wid) * 8 + lrow8;
            async_ld16(kc + (size_t)(b * SEQ + kt * 128 + row) * EMB + h * HD + gcK * 8,
                       &Ks[(it * 4 + wid) * 512]);
        }
#pragma unroll
        for (int it = 0; it < 4; ++it) {   // V: 64 d-rows x 128 t
            int row = (it * 4 + wid) * 4 + (lane >> 4);
            int gc  = (lane & 15) ^ (row & 15);
            async_ld16(vbase + (size_t)row * SEQ + kt * 128 + gc * 8,
                       &Vs[(it * 4 + wid) * 512]);
        }
        __syncthreads();

        float4v s[8];
#pragma unroll
        for (int j = 0; j < 8; j++) {
            s[j] = (float4v)0.f;
#pragma unroll
            for (int ks = 0; ks < 2; ks++) {
                int row = j * 16 + (lane & 15);
                int c   = ks * 4 + (lane >> 4);
                short8 kf = *(const short8*)&Ks[row * 64 + ((c ^ (row & 7)) * 8)];
                s[j] = __builtin_amdgcn_mfma_f32_16x16x32_bf16(qf[ks], kf, s[j], 0, 0, 0);
            }
        }

        // mask -> exp2 -> accumulate l, write P (C-layout -> A-layout via LDS)
#pragma unroll
        for (int j = 0; j < 8; j++) {
            int key = kt * 128 + j * 16 + (lane & 15);
            float mz = mask[b * SEQ + key] ? -1e30f : 0.0f;
            int prow = ((lane >> 4) << 2) * 136 + j * 16 + (lane & 15);
#pragma unroll
            for (int rr = 0; rr < 4; rr++) {
                float p = fast_exp2(s[j][rr] + mz);
                l_r[rr] += p;
                Pw[prow + rr * 136] = f2bf_rn(p);
            }
        }
        asm volatile("s_waitcnt lgkmcnt(0)" ::: "memory");   // wave-private RAW

        short8 pf[4];
#pragma unroll
        for (int ks = 0; ks < 4; ks++)
            pf[ks] = *(const short8*)&Pw[(lane & 15) * 136 + ks * 32 + (lane >> 4) * 8];

#pragma unroll
        for (int j = 0; j < 4; j++) {
            int d = j * 16 + (lane & 15);
#pragma unroll
            for (int ks = 0; ks < 4; ks++) {
                int c = ks * 4 + (lane >> 4);
                short8 vf = *(const short8*)&Vs[d * 128 + ((c ^ (d & 15)) * 8)];
                o[j] = __builtin_amdgcn_mfma_f32_16x16x32_bf16(pf[ks], vf, o[j], 0, 0, 0);
            }
        }
    }

#pragma unroll
    for (int rr = 0; rr < 4; rr++)
#pragma unroll
        for (int off = 1; off < 16; off <<= 1)
            l_r[rr] += __shfl_xor(l_r[rr], off, 64);

    const int qrow_out = qt * 64 + wid * 16 + ((lane >> 4) << 2);
#pragma unroll
    for (int j = 0; j < 4; j++) {
        int d = j * 16 + (lane & 15);
#pragma unroll
        for (int rr = 0; rr < 4; rr++) {
            float val = o[j][rr] / l_r[rr];
            out[((size_t)(b * SEQ + qrow_out + rr)) * EMB + h * HD + d] = f2bf(val);
        }
    }
}

// ---------------------------------------------------------------------------
extern "C" void kernel_launch(void* const* d_in, const int* in_sizes, int n_in,
                              void* d_out, int out_size, void* d_ws, size_t ws_size,
                              hipStream_t stream)
{
    const float* query = (const float*)d_in[0];
    const float* key_  = (const float*)d_in[1];
    const float* value = (const float*)d_in[2];
    const unsigned char* mask = (const unsigned char*)d_in[3];
    const float* Wq  = (const float*)d_in[4];
    const float* bq  = (const float*)d_in[5];
    const float* Wk  = (const float*)d_in[6];
    const float* bk  = (const float*)d_in[7];
    const float* Wv  = (const float*)d_in[8];
    const float* bv  = (const float*)d_in[9];
    const float* Wo  = (const float*)d_in[10];
    const float* bo  = (const float*)d_in[11];
    const float* cbq = (const float*)d_in[12];
    const float* cbk = (const float*)d_in[13];

    ushort* ws = (ushort*)d_ws;
    const size_t n1 = (size_t)BT * EMB;   // 4M elems
    const size_t nw = (size_t)EMB * EMB;  // 1M elems
    ushort* qb  = ws;
    ushort* kb  = qb  + n1;
    ushort* vb  = kb  + n1;
    ushort* wqb = vb  + n1;
    ushort* wkb = wqb + nw;
    ushort* wvb = wkb + nw;
    ushort* wob = wvb + nw;
    ushort* qc  = wob + nw;           // (B*T, EMB) centered, *log2e/8 (row-major)
    ushort* kc  = qc  + n1;           // (B*T, EMB) centered (row-major)
    ushort* vt  = kc  + n1;           // (B,H,D,T)
    ushort* ao  = qb;                 // reuse qb slot (stream-serialized)

    cvt_all<<<8192, 256, 0, stream>>>(query, key_, value, Wq, Wk, Wv, Wo,
                                      qb, kb, vb, wqb, wkb, wvb, wob);

    gemm_qkv<<<768, 256, 0, stream>>>(qb, kb, vb, wqb, wkb, wvb,
                                      bq, bk, bv, cbq, cbk, qc, kc, vt);

    attn_kernel<<<BATCH * HEADS * (SEQ / 64), 256, 0, stream>>>(qc, kc, vt, mask, ao);

    dim3 go(EMB / 128, BT / 64);
    gemm_out<<<go, 256, 0, stream>>>(ao, wob, bo, (float*)d_out);
}